// Round 3
// baseline (145.051 us; speedup 1.0000x reference)
//
#include <hip/hip_runtime.h>
#include <hip/hip_bf16.h>
#include <math.h>

#define NVARS 512
#define HID   16
#define TOPK  8

// ---------------- Kernel 1: routing (Q/K proj, sim, top-8, softmax) ----------
// Grid: 64 blocks x 512 threads. Wave w of block b handles row n = b*8 + w.
__global__ __launch_bounds__(512) void routing_kernel(
    const float* __restrict__ ve,   // (512,16)
    const float* __restrict__ Wq,   // (16,16)
    const float* __restrict__ bq,   // (16,)
    const float* __restrict__ Wk,   // (16,16)
    const float* __restrict__ bk,   // (16,)
    int*   __restrict__ out_idx,    // (512,8)
    float* __restrict__ out_w)      // (512,8)
{
    __shared__ float Ks[NVARS][HID + 1];   // stride 17 -> conflict-free

    const int t    = threadIdx.x;          // 0..511
    const int wave = t >> 6;               // 0..7
    const int lane = t & 63;
    const int n    = blockIdx.x * 8 + wave;  // row this wave owns

    // --- K[t][:] into LDS (each thread computes one K row) ---
    float vrow[HID];
    #pragma unroll
    for (int j = 0; j < HID; ++j) vrow[j] = ve[t * HID + j];
    #pragma unroll
    for (int h = 0; h < HID; ++h) {
        float s = bk[h];
        #pragma unroll
        for (int j = 0; j < HID; ++j) s += vrow[j] * Wk[h * HID + j];
        Ks[t][h] = s;
    }

    // --- Q[n][:] redundantly per lane (uniform loads, broadcast) ---
    float q[HID];
    #pragma unroll
    for (int j = 0; j < HID; ++j) vrow[j] = ve[n * HID + j];
    #pragma unroll
    for (int h = 0; h < HID; ++h) {
        float s = bq[h];
        #pragma unroll
        for (int j = 0; j < HID; ++j) s += vrow[j] * Wq[h * HID + j];
        q[h] = s;
    }

    __syncthreads();

    // --- sims for m = i*64 + lane (8 per lane = full 512 per wave) ---
    float vals[8];
    #pragma unroll
    for (int i = 0; i < 8; ++i) {
        const int m = i * 64 + lane;
        float s = 0.f;
        #pragma unroll
        for (int h = 0; h < HID; ++h) s += q[h] * Ks[m][h];
        vals[i] = (m == n) ? -1.0e9f : s;
    }

    // --- 8 rounds of wave-wide argmax (top-8) ---
    float mx = 0.f, my_val = 0.f, sum_exp = 0.f;
    int my_idx = 0;
    #pragma unroll
    for (int r = 0; r < TOPK; ++r) {
        float bv = vals[0];
        int   bi = lane;                    // m = 0*64 + lane
        #pragma unroll
        for (int i = 1; i < 8; ++i) {
            const int m = i * 64 + lane;
            if (vals[i] > bv) { bv = vals[i]; bi = m; }   // strict > keeps lowest m on tie
        }
        #pragma unroll
        for (int off = 32; off >= 1; off >>= 1) {
            const float ov = __shfl_xor(bv, off);
            const int   oi = __shfl_xor(bi, off);
            if (ov > bv || (ov == bv && oi < bi)) { bv = ov; bi = oi; }
        }
        // all lanes now hold round-r winner (bv, bi)
        if (r == 0) mx = bv;
        sum_exp += __expf(bv - mx);
        if (lane == r) { my_val = bv; my_idx = bi; }
        // owner lane retires the winner
        if ((bi & 63) == lane) {
            const int slot = bi >> 6;
            #pragma unroll
            for (int i = 0; i < 8; ++i)
                if (slot == i) vals[i] = -3.4e38f;
        }
    }

    if (lane < TOPK) {
        out_idx[n * TOPK + lane] = my_idx;
        out_w[n * TOPK + lane]   = __expf(my_val - mx) / sum_exp;
    }
}

// ---------------- Kernel 2: gather-weighted sum over rows --------------------
// Grid: 2048 blocks x 256 threads (4 waves). Each wave owns a PRIVATE 8 KB
// transposed LDS buffer holding its own 4 rows: buf[col] = float4(r0..r3 at
// col). ds_write -> ds_read stays within one wave, so NO __syncthreads() is
// needed anywhere (compiler emits lgkmcnt waits). One random-column gather is
// a single ds_read_b128 serving 4 rows.
__global__ __launch_bounds__(256) void apply_kernel(
    const float* __restrict__ x,     // (32768, 512)
    const int*   __restrict__ gidx,  // (512, 8)
    const float* __restrict__ gw,    // (512, 8)
    float*       __restrict__ out)   // (32768, 512)
{
    __shared__ float4 xs[4][NVARS];  // 4 waves x 8 KB, wave-private

    const int t    = threadIdx.x;
    const int wave = t >> 6;
    const int lane = t & 63;
    float4* buf = xs[wave];

    const long row0 = (long)blockIdx.x * 16 + wave * 4;   // this wave's 4 rows
    const float* xp = x + row0 * NVARS;

    // Load 4 rows, columns lane + 64*i (each load: 64 consecutive dwords,
    // fully coalesced). All 32 loads issued before any LDS write -> deep MLP.
    float4 v[8];
    #pragma unroll
    for (int i = 0; i < 8; ++i) {
        const int c = i * 64 + lane;
        v[i].x = xp[0 * NVARS + c];
        v[i].y = xp[1 * NVARS + c];
        v[i].z = xp[2 * NVARS + c];
        v[i].w = xp[3 * NVARS + c];
    }
    #pragma unroll
    for (int i = 0; i < 8; ++i)
        buf[i * 64 + lane] = v[i];      // conflict-free ds_write_b128

    // Gather: thread owns columns c = lane + 64*i.
    #pragma unroll
    for (int i = 0; i < 8; ++i) {
        const int c = i * 64 + lane;
        const int4   i0 = ((const int4*)gidx)[2 * c + 0];
        const int4   i1 = ((const int4*)gidx)[2 * c + 1];
        const float4 w0 = ((const float4*)gw)[2 * c + 0];
        const float4 w1 = ((const float4*)gw)[2 * c + 1];

        float ax = 0.f, ay = 0.f, az = 0.f, aw = 0.f;
        float4 g;
        g = buf[i0.x]; ax += g.x * w0.x; ay += g.y * w0.x; az += g.z * w0.x; aw += g.w * w0.x;
        g = buf[i0.y]; ax += g.x * w0.y; ay += g.y * w0.y; az += g.z * w0.y; aw += g.w * w0.y;
        g = buf[i0.z]; ax += g.x * w0.z; ay += g.y * w0.z; az += g.z * w0.z; aw += g.w * w0.z;
        g = buf[i0.w]; ax += g.x * w0.w; ay += g.y * w0.w; az += g.z * w0.w; aw += g.w * w0.w;
        g = buf[i1.x]; ax += g.x * w1.x; ay += g.y * w1.x; az += g.z * w1.x; aw += g.w * w1.x;
        g = buf[i1.y]; ax += g.x * w1.y; ay += g.y * w1.y; az += g.z * w1.y; aw += g.w * w1.y;
        g = buf[i1.z]; ax += g.x * w1.z; ay += g.y * w1.z; az += g.z * w1.z; aw += g.w * w1.z;
        g = buf[i1.w]; ax += g.x * w1.w; ay += g.y * w1.w; az += g.z * w1.w; aw += g.w * w1.w;

        float* o = out + row0 * NVARS + c;
        o[0 * NVARS] = ax;
        o[1 * NVARS] = ay;
        o[2 * NVARS] = az;
        o[3 * NVARS] = aw;
    }
}

extern "C" void kernel_launch(void* const* d_in, const int* in_sizes, int n_in,
                              void* d_out, int out_size, void* d_ws, size_t ws_size,
                              hipStream_t stream) {
    const float* x  = (const float*)d_in[0];   // (8,4096,512)
    const float* ve = (const float*)d_in[1];   // (512,16)
    const float* Wq = (const float*)d_in[2];   // (16,16)
    const float* bq = (const float*)d_in[3];   // (16,)
    const float* Wk = (const float*)d_in[4];   // (16,16)
    const float* bk = (const float*)d_in[5];   // (16,)
    float* out = (float*)d_out;

    int*   idx_ws = (int*)d_ws;
    float* w_ws   = (float*)((char*)d_ws + NVARS * TOPK * sizeof(int));

    routing_kernel<<<64, 512, 0, stream>>>(ve, Wq, bq, Wk, bk, idx_ws, w_ws);
    apply_kernel<<<2048, 256, 0, stream>>>(x, idx_ws, w_ws, out);
}

// Round 4
// 144.869 us; speedup vs baseline: 1.0013x; 1.0013x over previous
//
#include <hip/hip_runtime.h>
#include <hip/hip_bf16.h>
#include <math.h>

#define NVARS 512
#define HID   16
#define TOPK  8

// ---------------- Kernel 1: routing (Q/K proj, sim, top-8, softmax) ----------
// Grid: 64 blocks x 512 threads. Wave w of block b handles row n = b*8 + w.
__global__ __launch_bounds__(512) void routing_kernel(
    const float* __restrict__ ve,   // (512,16)
    const float* __restrict__ Wq,   // (16,16)
    const float* __restrict__ bq,   // (16,)
    const float* __restrict__ Wk,   // (16,16)
    const float* __restrict__ bk,   // (16,)
    int*   __restrict__ out_idx,    // (512,8)
    float* __restrict__ out_w)      // (512,8)
{
    __shared__ float Ks[NVARS][HID + 1];   // stride 17 -> conflict-free

    const int t    = threadIdx.x;          // 0..511
    const int wave = t >> 6;               // 0..7
    const int lane = t & 63;
    const int n    = blockIdx.x * 8 + wave;  // row this wave owns

    // --- K[t][:] into LDS (each thread computes one K row) ---
    float vrow[HID];
    #pragma unroll
    for (int j = 0; j < HID; ++j) vrow[j] = ve[t * HID + j];
    #pragma unroll
    for (int h = 0; h < HID; ++h) {
        float s = bk[h];
        #pragma unroll
        for (int j = 0; j < HID; ++j) s += vrow[j] * Wk[h * HID + j];
        Ks[t][h] = s;
    }

    // --- Q[n][:] redundantly per lane (uniform loads, broadcast) ---
    float q[HID];
    #pragma unroll
    for (int j = 0; j < HID; ++j) vrow[j] = ve[n * HID + j];
    #pragma unroll
    for (int h = 0; h < HID; ++h) {
        float s = bq[h];
        #pragma unroll
        for (int j = 0; j < HID; ++j) s += vrow[j] * Wq[h * HID + j];
        q[h] = s;
    }

    __syncthreads();

    // --- sims for m = i*64 + lane (8 per lane = full 512 per wave) ---
    float vals[8];
    #pragma unroll
    for (int i = 0; i < 8; ++i) {
        const int m = i * 64 + lane;
        float s = 0.f;
        #pragma unroll
        for (int h = 0; h < HID; ++h) s += q[h] * Ks[m][h];
        vals[i] = (m == n) ? -1.0e9f : s;
    }

    // --- 8 rounds of wave-wide argmax (top-8) ---
    float mx = 0.f, my_val = 0.f, sum_exp = 0.f;
    int my_idx = 0;
    #pragma unroll
    for (int r = 0; r < TOPK; ++r) {
        float bv = vals[0];
        int   bi = lane;                    // m = 0*64 + lane
        #pragma unroll
        for (int i = 1; i < 8; ++i) {
            const int m = i * 64 + lane;
            if (vals[i] > bv) { bv = vals[i]; bi = m; }   // strict > keeps lowest m on tie
        }
        #pragma unroll
        for (int off = 32; off >= 1; off >>= 1) {
            const float ov = __shfl_xor(bv, off);
            const int   oi = __shfl_xor(bi, off);
            if (ov > bv || (ov == bv && oi < bi)) { bv = ov; bi = oi; }
        }
        // all lanes now hold round-r winner (bv, bi)
        if (r == 0) mx = bv;
        sum_exp += __expf(bv - mx);
        if (lane == r) { my_val = bv; my_idx = bi; }
        // owner lane retires the winner
        if ((bi & 63) == lane) {
            const int slot = bi >> 6;
            #pragma unroll
            for (int i = 0; i < 8; ++i)
                if (slot == i) vals[i] = -3.4e38f;
        }
    }

    if (lane < TOPK) {
        out_idx[n * TOPK + lane] = my_idx;
        out_w[n * TOPK + lane]   = __expf(my_val - mx) / sum_exp;
    }
}

// ---------------- Kernel 2: gather-weighted sum over rows --------------------
// R2 structure (best measured): 1024 blocks x 512 threads, 32 rows/block in
// groups of 4, TRANSPOSED double-buffered LDS (buf[col] = float4 of 4 rows ->
// one random gather = one ds_read_b128 serving 4 rows). 16 KB LDS -> 4
// blocks/CU = 32 waves/CU (R3's wave-private variant halved occupancy and
// regressed). New vs R2: ONE barrier per group instead of two (next-buffer
// write moved after compute; previous group's barrier + its implied
// lgkmcnt(0) drain protects WAR), and nontemporal x/out accesses (zero-reuse
// streaming data).
__global__ __launch_bounds__(512) void apply_kernel(
    const float* __restrict__ x,     // (32768, 512)
    const int*   __restrict__ gidx,  // (512, 8)
    const float* __restrict__ gw,    // (512, 8)
    float*       __restrict__ out)   // (32768, 512)
{
    __shared__ float4 xs[2][NVARS];  // 2 x 8 KB

    const int t = threadIdx.x;       // thread t owns column t (all rows)
    const int4   i0 = ((const int4*)gidx)[2 * t + 0];
    const int4   i1 = ((const int4*)gidx)[2 * t + 1];
    const float4 w0 = ((const float4*)gw)[2 * t + 0];
    const float4 w1 = ((const float4*)gw)[2 * t + 1];

    const long base = (long)blockIdx.x * 32;

    // preload group 0: column t of rows base..base+3 (coalesced dword loads)
    {
        const float* xp = x + base * NVARS + t;
        float4 v;
        v.x = __builtin_nontemporal_load(xp + 0 * NVARS);
        v.y = __builtin_nontemporal_load(xp + 1 * NVARS);
        v.z = __builtin_nontemporal_load(xp + 2 * NVARS);
        v.w = __builtin_nontemporal_load(xp + 3 * NVARS);
        xs[0][t] = v;                 // conflict-free ds_write_b128
    }
    __syncthreads();

    #pragma unroll 1
    for (int g = 0; g < 8; ++g) {
        const float4* buf = xs[g & 1];

        // issue next group's global loads early (latency overlapped w/ compute)
        float4 v;
        if (g < 7) {
            const float* xn = x + (base + 4 * (g + 1)) * NVARS + t;
            v.x = __builtin_nontemporal_load(xn + 0 * NVARS);
            v.y = __builtin_nontemporal_load(xn + 1 * NVARS);
            v.z = __builtin_nontemporal_load(xn + 2 * NVARS);
            v.w = __builtin_nontemporal_load(xn + 3 * NVARS);
        }

        float ax = 0.f, ay = 0.f, az = 0.f, aw = 0.f;
        float4 c;
        c = buf[i0.x]; ax += c.x * w0.x; ay += c.y * w0.x; az += c.z * w0.x; aw += c.w * w0.x;
        c = buf[i0.y]; ax += c.x * w0.y; ay += c.y * w0.y; az += c.z * w0.y; aw += c.w * w0.y;
        c = buf[i0.z]; ax += c.x * w0.z; ay += c.y * w0.z; az += c.z * w0.z; aw += c.w * w0.z;
        c = buf[i0.w]; ax += c.x * w0.w; ay += c.y * w0.w; az += c.z * w0.w; aw += c.w * w0.w;
        c = buf[i1.x]; ax += c.x * w1.x; ay += c.y * w1.x; az += c.z * w1.x; aw += c.w * w1.x;
        c = buf[i1.y]; ax += c.x * w1.y; ay += c.y * w1.y; az += c.z * w1.y; aw += c.w * w1.y;
        c = buf[i1.z]; ax += c.x * w1.z; ay += c.y * w1.z; az += c.z * w1.z; aw += c.w * w1.z;
        c = buf[i1.w]; ax += c.x * w1.w; ay += c.y * w1.w; az += c.z * w1.w; aw += c.w * w1.w;

        float* o = out + (base + 4 * g) * NVARS + t;
        __builtin_nontemporal_store(ax, o + 0 * NVARS);
        __builtin_nontemporal_store(ay, o + 1 * NVARS);
        __builtin_nontemporal_store(az, o + 2 * NVARS);
        __builtin_nontemporal_store(aw, o + 3 * NVARS);

        if (g < 7) {
            // write next buffer: its last readers were in iter g-1, separated
            // from this write by the barrier below (which also drained reads).
            xs[(g + 1) & 1][t] = v;
            __syncthreads();
        }
    }
}

extern "C" void kernel_launch(void* const* d_in, const int* in_sizes, int n_in,
                              void* d_out, int out_size, void* d_ws, size_t ws_size,
                              hipStream_t stream) {
    const float* x  = (const float*)d_in[0];   // (8,4096,512)
    const float* ve = (const float*)d_in[1];   // (512,16)
    const float* Wq = (const float*)d_in[2];   // (16,16)
    const float* bq = (const float*)d_in[3];   // (16,)
    const float* Wk = (const float*)d_in[4];   // (16,16)
    const float* bk = (const float*)d_in[5];   // (16,)
    float* out = (float*)d_out;

    int*   idx_ws = (int*)d_ws;
    float* w_ws   = (float*)((char*)d_ws + NVARS * TOPK * sizeof(int));

    routing_kernel<<<64, 512, 0, stream>>>(ve, Wq, bq, Wk, bk, idx_ws, w_ws);
    apply_kernel<<<1024, 512, 0, stream>>>(x, idx_ws, w_ws, out);
}

// Round 5
// 138.734 us; speedup vs baseline: 1.0455x; 1.0442x over previous
//
#include <hip/hip_runtime.h>
#include <hip/hip_bf16.h>
#include <math.h>

#define NVARS 512
#define HID   16
#define TOPK  8

// ---------------- Kernel 1: routing (Q/K proj, sim, top-8, softmax) ----------
// Grid: 64 blocks x 512 threads. Wave w of block b handles row n = b*8 + w.
__global__ __launch_bounds__(512) void routing_kernel(
    const float* __restrict__ ve,   // (512,16)
    const float* __restrict__ Wq,   // (16,16)
    const float* __restrict__ bq,   // (16,)
    const float* __restrict__ Wk,   // (16,16)
    const float* __restrict__ bk,   // (16,)
    int*   __restrict__ out_idx,    // (512,8)
    float* __restrict__ out_w)      // (512,8)
{
    __shared__ float Ks[NVARS][HID + 1];   // stride 17 -> conflict-free

    const int t    = threadIdx.x;          // 0..511
    const int wave = t >> 6;               // 0..7
    const int lane = t & 63;
    const int n    = blockIdx.x * 8 + wave;  // row this wave owns

    // --- K[t][:] into LDS (each thread computes one K row) ---
    float vrow[HID];
    #pragma unroll
    for (int j = 0; j < HID; ++j) vrow[j] = ve[t * HID + j];
    #pragma unroll
    for (int h = 0; h < HID; ++h) {
        float s = bk[h];
        #pragma unroll
        for (int j = 0; j < HID; ++j) s += vrow[j] * Wk[h * HID + j];
        Ks[t][h] = s;
    }

    // --- Q[n][:] redundantly per lane (uniform loads, broadcast) ---
    float q[HID];
    #pragma unroll
    for (int j = 0; j < HID; ++j) vrow[j] = ve[n * HID + j];
    #pragma unroll
    for (int h = 0; h < HID; ++h) {
        float s = bq[h];
        #pragma unroll
        for (int j = 0; j < HID; ++j) s += vrow[j] * Wq[h * HID + j];
        q[h] = s;
    }

    __syncthreads();

    // --- sims for m = i*64 + lane (8 per lane = full 512 per wave) ---
    float vals[8];
    #pragma unroll
    for (int i = 0; i < 8; ++i) {
        const int m = i * 64 + lane;
        float s = 0.f;
        #pragma unroll
        for (int h = 0; h < HID; ++h) s += q[h] * Ks[m][h];
        vals[i] = (m == n) ? -1.0e9f : s;
    }

    // --- 8 rounds of wave-wide argmax (top-8) ---
    float mx = 0.f, my_val = 0.f, sum_exp = 0.f;
    int my_idx = 0;
    #pragma unroll
    for (int r = 0; r < TOPK; ++r) {
        float bv = vals[0];
        int   bi = lane;                    // m = 0*64 + lane
        #pragma unroll
        for (int i = 1; i < 8; ++i) {
            const int m = i * 64 + lane;
            if (vals[i] > bv) { bv = vals[i]; bi = m; }   // strict > keeps lowest m on tie
        }
        #pragma unroll
        for (int off = 32; off >= 1; off >>= 1) {
            const float ov = __shfl_xor(bv, off);
            const int   oi = __shfl_xor(bi, off);
            if (ov > bv || (ov == bv && oi < bi)) { bv = ov; bi = oi; }
        }
        // all lanes now hold round-r winner (bv, bi)
        if (r == 0) mx = bv;
        sum_exp += __expf(bv - mx);
        if (lane == r) { my_val = bv; my_idx = bi; }
        // owner lane retires the winner
        if ((bi & 63) == lane) {
            const int slot = bi >> 6;
            #pragma unroll
            for (int i = 0; i < 8; ++i)
                if (slot == i) vals[i] = -3.4e38f;
        }
    }

    if (lane < TOPK) {
        out_idx[n * TOPK + lane] = my_idx;
        out_w[n * TOPK + lane]   = __expf(my_val - mx) / sum_exp;
    }
}

// ---------------- Kernel 2: gather-weighted sum over rows --------------------
// EXACT R2 winner (best measured: 139.1 us total). 1024 blocks x 512 threads;
// each block does 32 rows, 4 at a time. LDS is TRANSPOSED: xs[buf][col] =
// float4(row0..row3 value at col), so one random-column gather is a single
// ds_read_b128 serving 4 rows. Double-buffered, two barriers per group.
// Measured worse alternatives: wave-private LDS/256thr (R3, -6us: occupancy
// 20 vs 32 waves/CU), single-barrier + nontemporal + long-lived prefetch
// regs (R4, -6us). Do not "improve" this structure without re-measuring.
__global__ __launch_bounds__(512) void apply_kernel(
    const float* __restrict__ x,     // (32768, 512)
    const int*   __restrict__ gidx,  // (512, 8)
    const float* __restrict__ gw,    // (512, 8)
    float*       __restrict__ out)   // (32768, 512)
{
    __shared__ float4 xs[2][NVARS];  // 2 x 8 KB

    const int t = threadIdx.x;       // thread t owns column t (all rows)
    const int4   i0 = ((const int4*)gidx)[2 * t + 0];
    const int4   i1 = ((const int4*)gidx)[2 * t + 1];
    const float4 w0 = ((const float4*)gw)[2 * t + 0];
    const float4 w1 = ((const float4*)gw)[2 * t + 1];

    const long base = (long)blockIdx.x * 32;

    // preload group 0: column t of rows base..base+3 (coalesced dword loads)
    const float* xp = x + base * NVARS + t;
    float v0 = xp[0 * NVARS];
    float v1 = xp[1 * NVARS];
    float v2 = xp[2 * NVARS];
    float v3 = xp[3 * NVARS];

    #pragma unroll 1
    for (int g = 0; g < 8; ++g) {
        float4* buf = xs[g & 1];
        buf[t] = make_float4(v0, v1, v2, v3);   // conflict-free b128 write
        __syncthreads();

        // prefetch next group while computing this one
        if (g < 7) {
            const float* xn = x + (base + 4 * (g + 1)) * NVARS + t;
            v0 = xn[0 * NVARS];
            v1 = xn[1 * NVARS];
            v2 = xn[2 * NVARS];
            v3 = xn[3 * NVARS];
        }

        float ax = 0.f, ay = 0.f, az = 0.f, aw = 0.f;
        float4 c;
        c = buf[i0.x]; ax += c.x * w0.x; ay += c.y * w0.x; az += c.z * w0.x; aw += c.w * w0.x;
        c = buf[i0.y]; ax += c.x * w0.y; ay += c.y * w0.y; az += c.z * w0.y; aw += c.w * w0.y;
        c = buf[i0.z]; ax += c.x * w0.z; ay += c.y * w0.z; az += c.z * w0.z; aw += c.w * w0.z;
        c = buf[i0.w]; ax += c.x * w0.w; ay += c.y * w0.w; az += c.z * w0.w; aw += c.w * w0.w;
        c = buf[i1.x]; ax += c.x * w1.x; ay += c.y * w1.x; az += c.z * w1.x; aw += c.w * w1.x;
        c = buf[i1.y]; ax += c.x * w1.y; ay += c.y * w1.y; az += c.z * w1.y; aw += c.w * w1.y;
        c = buf[i1.z]; ax += c.x * w1.z; ay += c.y * w1.z; az += c.z * w1.z; aw += c.w * w1.z;
        c = buf[i1.w]; ax += c.x * w1.w; ay += c.y * w1.w; az += c.z * w1.w; aw += c.w * w1.w;

        float* o = out + (base + 4 * g) * NVARS + t;
        o[0 * NVARS] = ax;
        o[1 * NVARS] = ay;
        o[2 * NVARS] = az;
        o[3 * NVARS] = aw;

        __syncthreads();   // all reads of buf done before it's rewritten (g+2)
    }
}

extern "C" void kernel_launch(void* const* d_in, const int* in_sizes, int n_in,
                              void* d_out, int out_size, void* d_ws, size_t ws_size,
                              hipStream_t stream) {
    const float* x  = (const float*)d_in[0];   // (8,4096,512)
    const float* ve = (const float*)d_in[1];   // (512,16)
    const float* Wq = (const float*)d_in[2];   // (16,16)
    const float* bq = (const float*)d_in[3];   // (16,)
    const float* Wk = (const float*)d_in[4];   // (16,16)
    const float* bk = (const float*)d_in[5];   // (16,)
    float* out = (float*)d_out;

    int*   idx_ws = (int*)d_ws;
    float* w_ws   = (float*)((char*)d_ws + NVARS * TOPK * sizeof(int));

    routing_kernel<<<64, 512, 0, stream>>>(ve, Wq, bq, Wk, bk, idx_ws, w_ws);
    apply_kernel<<<1024, 512, 0, stream>>>(x, idx_ws, w_ws, out);
}